// Round 1
// baseline (197.995 us; speedup 1.0000x reference)
//
#include <hip/hip_runtime.h>
#include <stdint.h>

#define SEQ 2048
#define NH  16

typedef __bf16 bf16x8 __attribute__((ext_vector_type(8)));
typedef float  f32x4  __attribute__((ext_vector_type(4)));

__device__ __forceinline__ unsigned short f2bf(float f) {
  union { float f; uint32_t u; } v; v.f = f;
  uint32_t r = v.u + 0x7fffu + ((v.u >> 16) & 1u);
  return (unsigned short)(r >> 16);
}

__device__ __forceinline__ void gll16(const void* g, void* l) {
  __builtin_amdgcn_global_load_lds((const __attribute__((address_space(1))) void*)g,
                                   (__attribute__((address_space(3))) void*)l, 16, 0, 0);
}

__device__ __forceinline__ f32x4 mfma16(bf16x8 a, bf16x8 b, f32x4 c) {
  return __builtin_amdgcn_mfma_f32_16x16x32_bf16(a, b, c, 0, 0, 0);
}

// ---------------- fp32 -> bf16 convert ----------------
__global__ void cvt_bf16(const float* __restrict__ src, unsigned short* __restrict__ dst, int n4) {
  int i = blockIdx.x * blockDim.x + threadIdx.x;
  int st = gridDim.x * blockDim.x;
  for (; i < n4; i += st) {
    float4 v = ((const float4*)src)[i];
    union { unsigned short u[4]; uint2 q; } o;
    o.u[0] = f2bf(v.x); o.u[1] = f2bf(v.y); o.u[2] = f2bf(v.z); o.u[3] = f2bf(v.w);
    ((uint2*)dst)[i] = o.q;
  }
}

// ---------------- GEMM: C[m][n] = sum_k A[m][k]*W[n][k], +bias, *scale ----------------
// M=4096, N=1024, K=1024. Tile 64x128, BK=64, 4 waves (2x2 of 32x64).
// MODE 0: store bf16 [B,H,S,DK]; MODE 1: store bf16 [B,H,DK,S]; MODE 2: store fp32 [M][N].
template<int MODE>
__global__ __launch_bounds__(256, 2) void gemm_bt(const unsigned short* __restrict__ A,
                                                  const unsigned short* __restrict__ W,
                                                  const float* __restrict__ bias,
                                                  void* __restrict__ outp, float scale) {
  __shared__ alignas(16) unsigned short Asm[64 * 64];    // [row][64k], chunk-swizzled
  __shared__ alignas(16) unsigned short Bsm[128 * 64];
  const int tid = threadIdx.x;
  const int l = tid & 63, w = tid >> 6;
  const int wr = w >> 1, wc = w & 1;
  const int lg = l >> 4, lo = l & 15;
  const int m0 = blockIdx.x * 64, n0 = blockIdx.y * 128;

  f32x4 acc[2][4] = {};

  for (int kt = 0; kt < 16; ++kt) {
    __syncthreads();
    // stage A: 64 rows x 8 chunks(16B) = 512 chunks, swizzled source
#pragma unroll
    for (int it = 0; it < 2; ++it) {
      int chunk = it * 256 + tid;
      int row = chunk >> 3, c = chunk & 7;
      const char* src = (const char*)A + (((size_t)(m0 + row) << 10) + (kt << 6)) * 2 + ((c ^ (row & 7)) << 4);
      gll16(src, (char*)Asm + ((it * 256 + (tid & ~63)) << 4));
    }
    // stage B (W rows): 128 x 8 = 1024 chunks
#pragma unroll
    for (int it = 0; it < 4; ++it) {
      int chunk = it * 256 + tid;
      int row = chunk >> 3, c = chunk & 7;
      const char* src = (const char*)W + (((size_t)(n0 + row) << 10) + (kt << 6)) * 2 + ((c ^ (row & 7)) << 4);
      gll16(src, (char*)Bsm + ((it * 256 + (tid & ~63)) << 4));
    }
    __syncthreads();
#pragma unroll
    for (int kf = 0; kf < 2; ++kf) {
      bf16x8 af[2], bfr[4];
#pragma unroll
      for (int mf = 0; mf < 2; ++mf) {
        int row = wr * 32 + mf * 16 + lo;
        int pos = (kf * 4 + lg) ^ (row & 7);
        af[mf] = *(const bf16x8*)((const char*)Asm + row * 128 + pos * 16);
      }
#pragma unroll
      for (int nf = 0; nf < 4; ++nf) {
        int row = wc * 64 + nf * 16 + lo;
        int pos = (kf * 4 + lg) ^ (row & 7);
        bfr[nf] = *(const bf16x8*)((const char*)Bsm + row * 128 + pos * 16);
      }
#pragma unroll
      for (int mf = 0; mf < 2; ++mf)
#pragma unroll
        for (int nf = 0; nf < 4; ++nf)
          acc[mf][nf] = mfma16(af[mf], bfr[nf], acc[mf][nf]);
    }
  }
  // epilogue
#pragma unroll
  for (int mf = 0; mf < 2; ++mf)
#pragma unroll
    for (int nf = 0; nf < 4; ++nf) {
      int gcol = n0 + wc * 64 + nf * 16 + lo;
      float bv = bias[gcol];
#pragma unroll
      for (int r = 0; r < 4; ++r) {
        int grow = m0 + wr * 32 + mf * 16 + lg * 4 + r;
        float v = (acc[mf][nf][r] + bv) * scale;
        if (MODE == 2) {
          ((float*)outp)[((size_t)grow << 10) + gcol] = v;
        } else {
          int b = grow >> 11, s = grow & 2047, h = gcol >> 6, dk = gcol & 63;
          size_t idx;
          if (MODE == 0) idx = ((((size_t)((b << 4) + h) << 11) + s) << 6) + dk;
          else           idx = ((((size_t)((b << 4) + h) << 6) + dk) << 11) + s;
          ((unsigned short*)outp)[idx] = f2bf(v);
        }
      }
    }
}

// ---------------- flash attention ----------------
// Qb,Kb: [B*H][S][64] bf16 (K pre-scaled by 0.125). Vt: [B*H][64][S] bf16.
// Grid: (S/128, B*H), 256 threads (4 waves x 32 q-rows). ctx: [B*S][1024] bf16.
__global__ __launch_bounds__(256, 2) void attn_kernel(const unsigned short* __restrict__ Qb,
                                                      const unsigned short* __restrict__ Kb,
                                                      const unsigned short* __restrict__ Vt,
                                                      unsigned short* __restrict__ ctx) {
  __shared__ alignas(16) unsigned short Ksm[64 * 64];   // [kv][64dk] swizzled
  __shared__ alignas(16) unsigned short Vsm[64 * 64];   // [dk][64kv] swizzled
  __shared__ alignas(16) unsigned short Psm[4 * 32 * 64]; // per-wave [32q][64kv] swizzled
  const int tid = threadIdx.x;
  const int l = tid & 63, w = tid >> 6;
  const int lg = l >> 4, lo = l & 15;
  const int bh = blockIdx.y;
  const unsigned short* Qp = Qb + (size_t)bh * SEQ * 64;
  const unsigned short* Kp = Kb + (size_t)bh * SEQ * 64;
  const unsigned short* Vp = Vt + (size_t)bh * 64 * SEQ;
  const int q0 = blockIdx.x * 128 + w * 32;

  // Q fragments in registers: rows q0+mf*16+lo, k = kf*32 + lg*8
  bf16x8 qf[2][2];
#pragma unroll
  for (int mf = 0; mf < 2; ++mf)
#pragma unroll
    for (int kf = 0; kf < 2; ++kf)
      qf[mf][kf] = *(const bf16x8*)((const char*)Qp + (((size_t)(q0 + mf * 16 + lo)) << 7) + kf * 64 + lg * 16);

  f32x4 O[2][4] = {};
  float mrow[2][4], lrow[2][4];
#pragma unroll
  for (int mf = 0; mf < 2; ++mf)
#pragma unroll
    for (int r = 0; r < 4; ++r) { mrow[mf][r] = -1e30f; lrow[mf][r] = 0.f; }

  for (int t = 0; t < SEQ / 64; ++t) {
    const int kv0 = t << 6;
    __syncthreads();
    // stage K-tile [64kv][64dk] and V-tile [64dk][64kv], swizzled sources
#pragma unroll
    for (int it = 0; it < 2; ++it) {
      int chunk = it * 256 + tid;
      int row = chunk >> 3, c = chunk & 7;
      const char* ksrc = (const char*)Kp + ((size_t)(kv0 + row) << 7) + ((c ^ (row & 7)) << 4);
      gll16(ksrc, (char*)Ksm + ((it * 256 + (tid & ~63)) << 4));
      const char* vsrc = (const char*)Vp + ((size_t)row << 12) + (kv0 << 1) + ((c ^ (row & 7)) << 4);
      gll16(vsrc, (char*)Vsm + ((it * 256 + (tid & ~63)) << 4));
    }
    __syncthreads();

    // S = Q K^T  (K pre-scaled)
    f32x4 sfr[2][4] = {};
#pragma unroll
    for (int kf = 0; kf < 2; ++kf) {
      bf16x8 bfr[4];
#pragma unroll
      for (int nf = 0; nf < 4; ++nf) {
        int kv = nf * 16 + lo;
        int pos = (kf * 4 + lg) ^ (kv & 7);
        bfr[nf] = *(const bf16x8*)((const char*)Ksm + kv * 128 + pos * 16);
      }
#pragma unroll
      for (int mf = 0; mf < 2; ++mf)
#pragma unroll
        for (int nf = 0; nf < 4; ++nf)
          sfr[mf][nf] = mfma16(qf[mf][kf], bfr[nf], sfr[mf][nf]);
    }

    // online softmax (rows = (lg*4+r) within each 16-row fragment)
#pragma unroll
    for (int mf = 0; mf < 2; ++mf) {
#pragma unroll
      for (int r = 0; r < 4; ++r) {
        float mx = fmaxf(fmaxf(sfr[mf][0][r], sfr[mf][1][r]), fmaxf(sfr[mf][2][r], sfr[mf][3][r]));
#pragma unroll
        for (int d = 1; d < 16; d <<= 1) mx = fmaxf(mx, __shfl_xor(mx, d));
        float mnew = fmaxf(mrow[mf][r], mx);
        float fac = __expf(mrow[mf][r] - mnew);
        mrow[mf][r] = mnew;
        float ps = 0.f;
#pragma unroll
        for (int nf = 0; nf < 4; ++nf) {
          float p = __expf(sfr[mf][nf][r] - mnew);
          sfr[mf][nf][r] = p;
          ps += p;
        }
#pragma unroll
        for (int d = 1; d < 16; d <<= 1) ps += __shfl_xor(ps, d);
        lrow[mf][r] = lrow[mf][r] * fac + ps;
#pragma unroll
        for (int dkf = 0; dkf < 4; ++dkf) O[mf][dkf][r] *= fac;
      }
      // write P fragment -> per-wave swizzled LDS (D-layout scatter)
#pragma unroll
      for (int r = 0; r < 4; ++r) {
        int ql = mf * 16 + lg * 4 + r;
        int base = w * 2048 + ql * 64;
        int sw = ql & 7;
#pragma unroll
        for (int nf = 0; nf < 4; ++nf) {
          int kv = nf * 16 + lo;
          Psm[base + (((kv >> 3) ^ sw) << 3) + (kv & 7)] = f2bf(sfr[mf][nf][r]);
        }
      }
    }

    // O += P V   (A-frags from Psm, B-frags from Vsm)
    bf16x8 af[2][2];
#pragma unroll
    for (int mf = 0; mf < 2; ++mf)
#pragma unroll
      for (int kc = 0; kc < 2; ++kc) {
        int ql = mf * 16 + lo;
        int pos = (kc * 4 + lg) ^ (ql & 7);
        af[mf][kc] = *(const bf16x8*)((const char*)Psm + w * 4096 + ql * 128 + pos * 16);
      }
#pragma unroll
    for (int dkf = 0; dkf < 4; ++dkf) {
      bf16x8 bvf[2];
#pragma unroll
      for (int kc = 0; kc < 2; ++kc) {
        int dk = dkf * 16 + lo;
        int pos = (kc * 4 + lg) ^ (dk & 7);
        bvf[kc] = *(const bf16x8*)((const char*)Vsm + dk * 128 + pos * 16);
      }
#pragma unroll
      for (int mf = 0; mf < 2; ++mf) {
        O[mf][dkf] = mfma16(af[mf][0], bvf[0], O[mf][dkf]);
        O[mf][dkf] = mfma16(af[mf][1], bvf[1], O[mf][dkf]);
      }
    }
  }

  // epilogue: normalize and store ctx [B*S][1024]
  const int b = bh >> 4, h = bh & 15;
#pragma unroll
  for (int mf = 0; mf < 2; ++mf)
#pragma unroll
    for (int r = 0; r < 4; ++r) {
      float inv = 1.f / lrow[mf][r];
      int srow = q0 + mf * 16 + lg * 4 + r;
      size_t rowoff = ((size_t)(b * SEQ + srow) << 10) + h * 64;
#pragma unroll
      for (int dkf = 0; dkf < 4; ++dkf)
        ctx[rowoff + dkf * 16 + lo] = f2bf(O[mf][dkf][r] * inv);
    }
}

// ---------------- launch ----------------
extern "C" void kernel_launch(void* const* d_in, const int* in_sizes, int n_in,
                              void* d_out, int out_size, void* d_ws, size_t ws_size,
                              hipStream_t stream) {
  const float* query = (const float*)d_in[0];
  const float* key_  = (const float*)d_in[1];
  const float* value = (const float*)d_in[2];
  const float* wq = (const float*)d_in[4];
  const float* bq = (const float*)d_in[5];
  const float* wk = (const float*)d_in[6];
  const float* bk = (const float*)d_in[7];
  const float* wv = (const float*)d_in[8];
  const float* bv = (const float*)d_in[9];
  const float* wo = (const float*)d_in[10];
  const float* bo = (const float*)d_in[11];
  float* out = (float*)d_out;

  char* ws = (char*)d_ws;
  unsigned short* xq  = (unsigned short*)(ws + 0);          // 4194304 elems
  unsigned short* xk  = (unsigned short*)(ws + 8388608);
  unsigned short* xv  = (unsigned short*)(ws + 16777216);
  unsigned short* wqb = (unsigned short*)(ws + 25165824);   // 1048576 elems each
  unsigned short* wkb = (unsigned short*)(ws + 27262976);
  unsigned short* wvb = (unsigned short*)(ws + 29360128);
  unsigned short* wob = (unsigned short*)(ws + 31457280);
  unsigned short* Qb  = (unsigned short*)(ws + 33554432);   // [B,H,S,64]
  unsigned short* Kb  = (unsigned short*)(ws + 41943040);   // [B,H,S,64] (pre-scaled)
  unsigned short* Vb  = (unsigned short*)(ws + 50331648);   // [B,H,64,S]
  unsigned short* ctx = (unsigned short*)(ws + 58720256);   // [B*S,1024]

  cvt_bf16<<<1024, 256, 0, stream>>>(query, xq, 1048576);
  cvt_bf16<<<1024, 256, 0, stream>>>(key_,  xk, 1048576);
  cvt_bf16<<<1024, 256, 0, stream>>>(value, xv, 1048576);
  cvt_bf16<<<512, 256, 0, stream>>>(wq, wqb, 262144);
  cvt_bf16<<<512, 256, 0, stream>>>(wk, wkb, 262144);
  cvt_bf16<<<512, 256, 0, stream>>>(wv, wvb, 262144);
  cvt_bf16<<<512, 256, 0, stream>>>(wo, wob, 262144);

  dim3 gg(64, 8);
  gemm_bt<0><<<gg, 256, 0, stream>>>(xq, wqb, bq, (void*)Qb, 1.0f);
  gemm_bt<0><<<gg, 256, 0, stream>>>(xk, wkb, bk, (void*)Kb, 0.125f);
  gemm_bt<1><<<gg, 256, 0, stream>>>(xv, wvb, bv, (void*)Vb, 1.0f);

  attn_kernel<<<dim3(16, 32), 256, 0, stream>>>(Qb, Kb, Vb, ctx);

  gemm_bt<2><<<gg, 256, 0, stream>>>(ctx, wob, bo, (void*)out, 1.0f);
}

// Round 2
// 157.253 us; speedup vs baseline: 1.2591x; 1.2591x over previous
//
#include <hip/hip_runtime.h>
#include <stdint.h>

#define SEQ 2048
#define NH  16

typedef __bf16 bf16x8 __attribute__((ext_vector_type(8)));
typedef float  f32x4  __attribute__((ext_vector_type(4)));

#if __has_builtin(__builtin_amdgcn_exp2f)
#define EXP2(x) __builtin_amdgcn_exp2f(x)
#else
#define EXP2(x) exp2f(x)
#endif

__device__ __forceinline__ unsigned short f2bf(float f) {
  union { float f; uint32_t u; } v; v.f = f;
  uint32_t r = v.u + 0x7fffu + ((v.u >> 16) & 1u);
  return (unsigned short)(r >> 16);
}

__device__ __forceinline__ void gll16(const void* g, void* l) {
  __builtin_amdgcn_global_load_lds((const __attribute__((address_space(1))) void*)g,
                                   (__attribute__((address_space(3))) void*)l, 16, 0, 0);
}

__device__ __forceinline__ f32x4 mfma16(bf16x8 a, bf16x8 b, f32x4 c) {
  return __builtin_amdgcn_mfma_f32_16x16x32_bf16(a, b, c, 0, 0, 0);
}

// ---------------- fp32 -> bf16 convert ----------------
__global__ void cvt_bf16(const float* __restrict__ src, unsigned short* __restrict__ dst, int n4) {
  int i = blockIdx.x * blockDim.x + threadIdx.x;
  int st = gridDim.x * blockDim.x;
  for (; i < n4; i += st) {
    float4 v = ((const float4*)src)[i];
    union { unsigned short u[4]; uint2 q; } o;
    o.u[0] = f2bf(v.x); o.u[1] = f2bf(v.y); o.u[2] = f2bf(v.z); o.u[3] = f2bf(v.w);
    ((uint2*)dst)[i] = o.q;
  }
}

// ---------------- GEMM: C[m][n] = sum_k A[m][k]*W[n][k], +bias, *scale ----------------
// M=4096, N=1024, K=1024. Tile 64x128, BK=64, 4 waves (2x2 of 32x64).
// MODE 0: store bf16 [B,H,S,DK]; MODE 1: store bf16 [B,H,DK,S]; MODE 2: store fp32 [M][N].
template<int MODE>
__global__ __launch_bounds__(256, 2) void gemm_bt(const unsigned short* __restrict__ A,
                                                  const unsigned short* __restrict__ W,
                                                  const float* __restrict__ bias,
                                                  void* __restrict__ outp, float scale) {
  __shared__ alignas(16) unsigned short Asm[64 * 64];    // [row][64k], chunk-swizzled
  __shared__ alignas(16) unsigned short Bsm[128 * 64];
  const int tid = threadIdx.x;
  const int l = tid & 63, w = tid >> 6;
  const int wr = w >> 1, wc = w & 1;
  const int lg = l >> 4, lo = l & 15;
  const int m0 = blockIdx.x * 64, n0 = blockIdx.y * 128;

  f32x4 acc[2][4] = {};

  for (int kt = 0; kt < 16; ++kt) {
    __syncthreads();
#pragma unroll
    for (int it = 0; it < 2; ++it) {
      int chunk = it * 256 + tid;
      int row = chunk >> 3, c = chunk & 7;
      const char* src = (const char*)A + (((size_t)(m0 + row) << 10) + (kt << 6)) * 2 + ((c ^ (row & 7)) << 4);
      gll16(src, (char*)Asm + ((it * 256 + (tid & ~63)) << 4));
    }
#pragma unroll
    for (int it = 0; it < 4; ++it) {
      int chunk = it * 256 + tid;
      int row = chunk >> 3, c = chunk & 7;
      const char* src = (const char*)W + (((size_t)(n0 + row) << 10) + (kt << 6)) * 2 + ((c ^ (row & 7)) << 4);
      gll16(src, (char*)Bsm + ((it * 256 + (tid & ~63)) << 4));
    }
    __syncthreads();
#pragma unroll
    for (int kf = 0; kf < 2; ++kf) {
      bf16x8 af[2], bfr[4];
#pragma unroll
      for (int mf = 0; mf < 2; ++mf) {
        int row = wr * 32 + mf * 16 + lo;
        int pos = (kf * 4 + lg) ^ (row & 7);
        af[mf] = *(const bf16x8*)((const char*)Asm + row * 128 + pos * 16);
      }
#pragma unroll
      for (int nf = 0; nf < 4; ++nf) {
        int row = wc * 64 + nf * 16 + lo;
        int pos = (kf * 4 + lg) ^ (row & 7);
        bfr[nf] = *(const bf16x8*)((const char*)Bsm + row * 128 + pos * 16);
      }
#pragma unroll
      for (int mf = 0; mf < 2; ++mf)
#pragma unroll
        for (int nf = 0; nf < 4; ++nf)
          acc[mf][nf] = mfma16(af[mf], bfr[nf], acc[mf][nf]);
    }
  }
#pragma unroll
  for (int mf = 0; mf < 2; ++mf)
#pragma unroll
    for (int nf = 0; nf < 4; ++nf) {
      int gcol = n0 + wc * 64 + nf * 16 + lo;
      float bv = bias[gcol];
#pragma unroll
      for (int r = 0; r < 4; ++r) {
        int grow = m0 + wr * 32 + mf * 16 + lg * 4 + r;
        float v = (acc[mf][nf][r] + bv) * scale;
        if (MODE == 2) {
          ((float*)outp)[((size_t)grow << 10) + gcol] = v;
        } else {
          int b = grow >> 11, s = grow & 2047, h = gcol >> 6, dk = gcol & 63;
          size_t idx;
          if (MODE == 0) idx = ((((size_t)((b << 4) + h) << 11) + s) << 6) + dk;
          else           idx = ((((size_t)((b << 4) + h) << 6) + dk) << 11) + s;
          ((unsigned short*)outp)[idx] = f2bf(v);
        }
      }
    }
}

// ---------------- flash attention (swapped QK^T: softmax lane-local) ----------------
// Qb: [B*H][S][64] bf16. Kb: [B*H][S][64] bf16 pre-scaled by 0.125*log2(e).
// Vt: [B*H][64][S] bf16. Grid: (S/128, B*H), 256 threads (4 waves x 32 q-rows).
__global__ __launch_bounds__(256, 2) void attn_kernel(const unsigned short* __restrict__ Qb,
                                                      const unsigned short* __restrict__ Kb,
                                                      const unsigned short* __restrict__ Vt,
                                                      unsigned short* __restrict__ ctx) {
  __shared__ alignas(16) unsigned short Ksm[64 * 64];     // [kv][64dk] swizzled
  __shared__ alignas(16) unsigned short Vsm[64 * 64];     // [dk][64kv] swizzled
  __shared__ alignas(16) unsigned short Psm[4 * 32 * 64]; // per-wave [32q][64kv] swizzled
  const int tid = threadIdx.x;
  const int l = tid & 63, w = tid >> 6;
  const int lg = l >> 4, lo = l & 15;
  const int bh = blockIdx.y;
  const unsigned short* Qp = Qb + (size_t)bh * SEQ * 64;
  const unsigned short* Kp = Kb + (size_t)bh * SEQ * 64;
  const unsigned short* Vp = Vt + (size_t)bh * 64 * SEQ;
  const int q0 = blockIdx.x * 128 + w * 32;

  // Q fragments: lane holds Q[q0 + qf*16 + lo][kc*32 + lg*8 ..+7]
  bf16x8 qf[2][2];
#pragma unroll
  for (int mf = 0; mf < 2; ++mf)
#pragma unroll
    for (int kc = 0; kc < 2; ++kc)
      qf[mf][kc] = *(const bf16x8*)((const char*)Qp + (((size_t)(q0 + mf * 16 + lo)) << 7) + kc * 64 + lg * 16);

  f32x4 O[2][4] = {};
  float m_[2], l_[2];
  m_[0] = m_[1] = -1e30f;
  l_[0] = l_[1] = 0.f;

  for (int t = 0; t < SEQ / 64; ++t) {
    const int kv0 = t << 6;
    __syncthreads();
#pragma unroll
    for (int it = 0; it < 2; ++it) {
      int chunk = it * 256 + tid;
      int row = chunk >> 3, c = chunk & 7;
      const char* ksrc = (const char*)Kp + ((size_t)(kv0 + row) << 7) + ((c ^ (row & 7)) << 4);
      gll16(ksrc, (char*)Ksm + ((it * 256 + (tid & ~63)) << 4));
      const char* vsrc = (const char*)Vp + ((size_t)row << 12) + (kv0 << 1) + ((c ^ (row & 7)) << 4);
      gll16(vsrc, (char*)Vsm + ((it * 256 + (tid & ~63)) << 4));
    }
    __syncthreads();

    // S^T = K Q^T : sfr[kvf][qf][r] = S[kv=kvf*16+lg*4+r][q=qf*16+lo]
    f32x4 sfr[4][2] = {};
#pragma unroll
    for (int kc = 0; kc < 2; ++kc) {
      bf16x8 kfr[4];
#pragma unroll
      for (int kvf = 0; kvf < 4; ++kvf) {
        int kv = kvf * 16 + lo;
        int pos = (kc * 4 + lg) ^ (kv & 7);
        kfr[kvf] = *(const bf16x8*)((const char*)Ksm + kv * 128 + pos * 16);
      }
#pragma unroll
      for (int kvf = 0; kvf < 4; ++kvf)
#pragma unroll
        for (int qfi = 0; qfi < 2; ++qfi)
          sfr[kvf][qfi] = mfma16(kfr[kvf], qf[qfi][kc], sfr[kvf][qfi]);
    }

    // online softmax: each lane owns q = qf*16+lo, 16 S-values (kv = kvf*16+lg*4+r)
    float tmx[2];
#pragma unroll
    for (int qfi = 0; qfi < 2; ++qfi) {
      float a0 = fmaxf(fmaxf(sfr[0][qfi][0], sfr[0][qfi][1]), fmaxf(sfr[0][qfi][2], sfr[0][qfi][3]));
      float a1 = fmaxf(fmaxf(sfr[1][qfi][0], sfr[1][qfi][1]), fmaxf(sfr[1][qfi][2], sfr[1][qfi][3]));
      float a2 = fmaxf(fmaxf(sfr[2][qfi][0], sfr[2][qfi][1]), fmaxf(sfr[2][qfi][2], sfr[2][qfi][3]));
      float a3 = fmaxf(fmaxf(sfr[3][qfi][0], sfr[3][qfi][1]), fmaxf(sfr[3][qfi][2], sfr[3][qfi][3]));
      float mx = fmaxf(fmaxf(a0, a1), fmaxf(a2, a3));
      mx = fmaxf(mx, __shfl_xor(mx, 16));
      mx = fmaxf(mx, __shfl_xor(mx, 32));
      tmx[qfi] = mx;
    }
    bool need = (tmx[0] > m_[0]) | (tmx[1] > m_[1]);
    if (__any((int)need)) {
      float facv[2];
#pragma unroll
      for (int qfi = 0; qfi < 2; ++qfi) {
        float mnew = fmaxf(m_[qfi], tmx[qfi]);
        facv[qfi] = EXP2(m_[qfi] - mnew);
        m_[qfi] = mnew;
        float ps = 0.f;
#pragma unroll
        for (int kvf = 0; kvf < 4; ++kvf)
#pragma unroll
          for (int r = 0; r < 4; ++r) {
            float p = EXP2(sfr[kvf][qfi][r] - mnew);
            sfr[kvf][qfi][r] = p;
            ps += p;
          }
        ps += __shfl_xor(ps, 16);
        ps += __shfl_xor(ps, 32);
        l_[qfi] = l_[qfi] * facv[qfi] + ps;
      }
#pragma unroll
      for (int mf = 0; mf < 2; ++mf)
#pragma unroll
        for (int r = 0; r < 4; ++r) {
          float fb = __shfl(facv[mf], lg * 4 + r);
#pragma unroll
          for (int dkf = 0; dkf < 4; ++dkf) O[mf][dkf][r] *= fb;
        }
    } else {
#pragma unroll
      for (int qfi = 0; qfi < 2; ++qfi) {
        float ps = 0.f;
#pragma unroll
        for (int kvf = 0; kvf < 4; ++kvf)
#pragma unroll
          for (int r = 0; r < 4; ++r) {
            float p = EXP2(sfr[kvf][qfi][r] - m_[qfi]);
            sfr[kvf][qfi][r] = p;
            ps += p;
          }
        ps += __shfl_xor(ps, 16);
        ps += __shfl_xor(ps, 32);
        l_[qfi] += ps;
      }
    }

    // pack P -> per-wave swizzled LDS [q 32][kv 64] (b64 writes, conflict-free)
#pragma unroll
    for (int qfi = 0; qfi < 2; ++qfi) {
      int ql = qfi * 16 + lo;
      int sw = ql & 7;
#pragma unroll
      for (int kvf = 0; kvf < 4; ++kvf) {
        union { __bf16 b[4]; unsigned long long u; } pk;
#pragma unroll
        for (int r = 0; r < 4; ++r) pk.b[r] = (__bf16)sfr[kvf][qfi][r];
        int g = kvf * 2 + (lg >> 1);
        *(unsigned long long*)((char*)Psm + w * 4096 + ql * 128 + ((g ^ sw) << 4) + ((lg & 1) << 3)) = pk.u;
      }
    }

    // O += P V : A-frags from Psm, B-frags from Vsm
    bf16x8 af[2][2];
#pragma unroll
    for (int mf = 0; mf < 2; ++mf)
#pragma unroll
      for (int kc = 0; kc < 2; ++kc) {
        int ql = mf * 16 + lo;
        int pos = (kc * 4 + lg) ^ (ql & 7);
        af[mf][kc] = *(const bf16x8*)((const char*)Psm + w * 4096 + ql * 128 + pos * 16);
      }
#pragma unroll
    for (int dkf = 0; dkf < 4; ++dkf) {
      bf16x8 bvf[2];
#pragma unroll
      for (int kc = 0; kc < 2; ++kc) {
        int dk = dkf * 16 + lo;
        int pos = (kc * 4 + lg) ^ (dk & 7);
        bvf[kc] = *(const bf16x8*)((const char*)Vsm + dk * 128 + pos * 16);
      }
#pragma unroll
      for (int mf = 0; mf < 2; ++mf) {
        O[mf][dkf] = mfma16(af[mf][0], bvf[0], O[mf][dkf]);
        O[mf][dkf] = mfma16(af[mf][1], bvf[1], O[mf][dkf]);
      }
    }
  }

  // epilogue: normalize and store ctx [B*S][1024]
  const int b = bh >> 4, h = bh & 15;
#pragma unroll
  for (int mf = 0; mf < 2; ++mf)
#pragma unroll
    for (int r = 0; r < 4; ++r) {
      float lr = __shfl(l_[mf], lg * 4 + r);
      float inv = 1.f / lr;
      int srow = q0 + mf * 16 + lg * 4 + r;
      size_t rowoff = ((size_t)(b * SEQ + srow) << 10) + h * 64;
#pragma unroll
      for (int dkf = 0; dkf < 4; ++dkf)
        ctx[rowoff + dkf * 16 + lo] = f2bf(O[mf][dkf][r] * inv);
    }
}

// ---------------- launch ----------------
extern "C" void kernel_launch(void* const* d_in, const int* in_sizes, int n_in,
                              void* d_out, int out_size, void* d_ws, size_t ws_size,
                              hipStream_t stream) {
  const float* query = (const float*)d_in[0];
  const float* key_  = (const float*)d_in[1];
  const float* value = (const float*)d_in[2];
  const float* wq = (const float*)d_in[4];
  const float* bq = (const float*)d_in[5];
  const float* wk = (const float*)d_in[6];
  const float* bk = (const float*)d_in[7];
  const float* wv = (const float*)d_in[8];
  const float* bv = (const float*)d_in[9];
  const float* wo = (const float*)d_in[10];
  const float* bo = (const float*)d_in[11];
  float* out = (float*)d_out;

  char* ws = (char*)d_ws;
  unsigned short* xq  = (unsigned short*)(ws + 0);
  unsigned short* xk  = (unsigned short*)(ws + 8388608);
  unsigned short* xv  = (unsigned short*)(ws + 16777216);
  unsigned short* wqb = (unsigned short*)(ws + 25165824);
  unsigned short* wkb = (unsigned short*)(ws + 27262976);
  unsigned short* wvb = (unsigned short*)(ws + 29360128);
  unsigned short* wob = (unsigned short*)(ws + 31457280);
  unsigned short* Qb  = (unsigned short*)(ws + 33554432);   // [B,H,S,64]
  unsigned short* Kb  = (unsigned short*)(ws + 41943040);   // [B,H,S,64] (pre-scaled, log2e folded)
  unsigned short* Vb  = (unsigned short*)(ws + 50331648);   // [B,H,64,S]
  unsigned short* ctx = (unsigned short*)(ws + 58720256);   // [B*S,1024]

  cvt_bf16<<<1024, 256, 0, stream>>>(query, xq, 1048576);
  cvt_bf16<<<1024, 256, 0, stream>>>(key_,  xk, 1048576);
  cvt_bf16<<<1024, 256, 0, stream>>>(value, xv, 1048576);
  cvt_bf16<<<512, 256, 0, stream>>>(wq, wqb, 262144);
  cvt_bf16<<<512, 256, 0, stream>>>(wk, wkb, 262144);
  cvt_bf16<<<512, 256, 0, stream>>>(wv, wvb, 262144);
  cvt_bf16<<<512, 256, 0, stream>>>(wo, wob, 262144);

  dim3 gg(64, 8);
  // K pre-scale: 1/sqrt(64) * log2(e) so softmax runs in base-2 domain
  const float kscale = 0.125f * 1.44269504088896340736f;
  gemm_bt<0><<<gg, 256, 0, stream>>>(xq, wqb, bq, (void*)Qb, 1.0f);
  gemm_bt<0><<<gg, 256, 0, stream>>>(xk, wkb, bk, (void*)Kb, kscale);
  gemm_bt<1><<<gg, 256, 0, stream>>>(xv, wvb, bv, (void*)Vb, 1.0f);

  attn_kernel<<<dim3(16, 32), 256, 0, stream>>>(Qb, Kb, Vb, ctx);

  gemm_bt<2><<<gg, 256, 0, stream>>>(ctx, wob, bo, (void*)out, 1.0f);
}